// Round 18
// baseline (86.035 us; speedup 1.0000x reference)
//
#include <hip/hip_runtime.h>
#include <stdint.h>

#define BB    4096
#define KS    8
#define PP    768
#define SLOT  256
#define HID   256
#define NC    512
#define BKROWS (BB*KS)          // 32768
typedef unsigned short u16;
typedef short bf16x8 __attribute__((ext_vector_type(8)));
typedef float f32x4  __attribute__((ext_vector_type(4)));

__device__ __forceinline__ u16 f2bf(float x) {
  union { float f; uint32_t u; } v; v.f = x;
  return (u16)((v.u + 0x7FFFu + ((v.u >> 16) & 1u)) >> 16);
}
__device__ __forceinline__ float bf2f(u16 x) {
  union { uint32_t u; float f; } v; v.u = (uint32_t)x << 16; return v.f;
}
__device__ __forceinline__ u16 f2h(float x) {
  union { _Float16 h; u16 u; } cv; cv.h = (_Float16)x; return cv.u;
}
__device__ __forceinline__ float h2f(u16 x) {
  union { u16 u; _Float16 h; } cv; cv.u = x; return (float)cv.h;
}

// XCD-aware bijective swizzle for grids with n % 8 == 0
__device__ __forceinline__ int xcd_swz(int bid, int n) {
  int cpx = n >> 3;
  return (bid & 7) * cpx + (bid >> 3);
}

__device__ __forceinline__ void gload_lds16(u16* ldst, const u16* gsrc) {
  __builtin_amdgcn_global_load_lds(
      (const __attribute__((address_space(1))) void*)gsrc,
      (__attribute__((address_space(3))) void*)ldst, 16, 0, 0);
}

// ---------------------------------------------------------------------------
// GEMM core 64x64: BM=BN=64, BK=64, 4 waves (2Mx2N), wave 32x32. acc 16 regs.
// EPI: 2 = bf16; 3 = +bias f32; 5 = +bias f16; 6 = +bias bf16.  [R12-verified]
// ---------------------------------------------------------------------------
template<int EPI>
__device__ __forceinline__ void gemm_core6464(
    const u16* __restrict__ A, int lda,
    const u16* __restrict__ B, int ldb,
    const float* __restrict__ bias,
    void* __restrict__ out, int ldo, int K,
    int blockRow, int blockCol, u16* lsA, u16* lsB)
{
  const int tid  = threadIdx.x;
  const int w    = tid >> 6;
  const int lane = tid & 63;
  const int wm   = w >> 1, wn = w & 1;
  const int rl   = lane >> 4, cl = lane & 15;

  f32x4 acc[2][2];
  const f32x4 zero = {0.f, 0.f, 0.f, 0.f};
#pragma unroll
  for (int i = 0; i < 2; ++i)
#pragma unroll
    for (int j = 0; j < 2; ++j) acc[i][j] = zero;

  const u16* Ablk = A + (size_t)blockRow * lda;
  const u16* Bblk = B + (size_t)blockCol * ldb;

  for (int k0 = 0; k0 < K; k0 += 64) {
#pragma unroll
    for (int i = 0; i < 2; ++i) {
      int seg   = i * 4 + w;
      int off16 = seg * 64 + lane;
      int row   = off16 >> 3;
      int chunk = (off16 & 7) ^ (row & 7);
      gload_lds16(lsA + seg * 512, Ablk + (size_t)row * lda + k0 + chunk * 8);
    }
#pragma unroll
    for (int i = 0; i < 2; ++i) {
      int seg   = i * 4 + w;
      int off16 = seg * 64 + lane;
      int row   = off16 >> 3;
      int chunk = (off16 & 7) ^ (row & 7);
      gload_lds16(lsB + seg * 512, Bblk + (size_t)row * ldb + k0 + chunk * 8);
    }
    __syncthreads();

#pragma unroll
    for (int ks = 0; ks < 2; ++ks) {
      bf16x8 aF[2], bF[2];
#pragma unroll
      for (int f = 0; f < 2; ++f) {
        int r  = wm * 32 + f * 16 + cl;
        int ca = ((ks * 4 + rl) ^ (r & 7)) * 8;
        aF[f] = *(const bf16x8*)(lsA + r * 64 + ca);
        int rn = wn * 32 + f * 16 + cl;
        int cb = ((ks * 4 + rl) ^ (rn & 7)) * 8;
        bF[f] = *(const bf16x8*)(lsB + rn * 64 + cb);
      }
#pragma unroll
      for (int fm = 0; fm < 2; ++fm)
#pragma unroll
        for (int fn = 0; fn < 2; ++fn)
          acc[fm][fn] = __builtin_amdgcn_mfma_f32_16x16x32_bf16(
              aF[fm], bF[fn], acc[fm][fn], 0, 0, 0);
    }
    __syncthreads();
  }

#pragma unroll
  for (int fm = 0; fm < 2; ++fm) {
#pragma unroll
    for (int fn = 0; fn < 2; ++fn) {
      f32x4 v = acc[fm][fn];
#pragma unroll
      for (int r = 0; r < 4; ++r) {
        int grow = blockRow + wm * 32 + fm * 16 + rl * 4 + r;
        int gcol = blockCol + wn * 32 + fn * 16 + cl;
        float x = v[r];
        if constexpr (EPI == 2) {
          ((u16*)out)[(size_t)grow * ldo + gcol] = f2bf(x);
        } else if constexpr (EPI == 3) {
          x += bias[gcol];
          ((float*)out)[(size_t)grow * ldo + gcol] = x;
        } else if constexpr (EPI == 5) {
          x += bias[gcol];
          ((u16*)out)[(size_t)grow * ldo + gcol] = f2h(x);
        } else if constexpr (EPI == 6) {
          x += bias[gcol];
          ((u16*)out)[(size_t)grow * ldo + gcol] = f2bf(x);
        }
      }
    }
  }
}

// ---------------------------------------------------------------------------
// prep_all (R12 layout)
// ---------------------------------------------------------------------------
__device__ __forceinline__ void cvt_seg(const float* __restrict__ in,
                                        u16* __restrict__ outp, int b, int n4) {
  int i = b * 256 + threadIdx.x;
  if (i < n4) {
    float4 v = ((const float4*)in)[i];
    ushort4 o;
    o.x = f2bf(v.x); o.y = f2bf(v.y); o.z = f2bf(v.z); o.w = f2bf(v.w);
    ((ushort4*)outp)[i] = o;
  }
}

__device__ __forceinline__ void pack_seg(const float* __restrict__ s0,
                                         const float* __restrict__ s1,
                                         u16* __restrict__ dst, int b) {
  int br = b >> 4, ng = b & 15;
  const float* src = br ? s1 : s0;
  int w = threadIdx.x >> 6, lane = threadIdx.x & 63;
  int rl = lane >> 4, cl = lane & 15;
#pragma unroll
  for (int s = 0; s < 2; ++s) {
    int step = w * 2 + s;
    union { u16 u[8]; uint4 q; } o;
#pragma unroll
    for (int j = 0; j < 8; ++j)
      o.u[j] = f2bf(src[(size_t)(step * 32 + rl * 8 + j) * 256 + ng * 16 + cl]);
    *(uint4*)(dst + (size_t)(((br * 16 + ng) * 8 + step) * 64 + lane) * 8) = o.q;
  }
}

__global__ __launch_bounds__(256) void prep_all(
    const float* __restrict__ inst, const float* __restrict__ Kc,
    const float* __restrict__ Kp, const float* __restrict__ Wfc,
    const float* __restrict__ Wfp, const float* __restrict__ Vc,
    const float* __restrict__ Vp, const float* __restrict__ pW1,
    const float* __restrict__ uW1, const float* __restrict__ pW2,
    const float* __restrict__ uW2, const float* __restrict__ bfc,
    const float* __restrict__ bfp,
    u16* instb, u16* Kcb, u16* Kpb, u16* Wfcb, u16* Wfpb, u16* Vcb, u16* Vpb,
    u16* W1Tp, u16* W1Tu, u16* W1pk, u16* W2pk, float* sb)
{
  __shared__ float tile[32][33];
  int b = blockIdx.x;
  if (b < 3072)      { cvt_seg(inst, instb, b,        786432); return; }
  else if (b < 3456) { cvt_seg(Kc,   Kcb,   b - 3072,  98304); return; }
  else if (b < 3840) { cvt_seg(Kp,   Kpb,   b - 3456,  98304); return; }
  else if (b < 4416) { cvt_seg(Wfc,  Wfcb,  b - 3840, 147456); return; }
  else if (b < 4992) { cvt_seg(Wfp,  Wfpb,  b - 4416, 147456); return; }
  else if (b < 5376) { cvt_seg(Vc,   Vcb,   b - 4992,  98304); return; }
  else if (b < 5760) { cvt_seg(Vp,   Vpb,   b - 5376,  98304); return; }
  else if (b < 6272) {
    int bb = b - 5760;
    const float* in = (bb < 256) ? pW1 : uW1;
    u16* outp = (bb < 256) ? W1Tp : W1Tu;
    bb &= 255;
    int tc = (bb & 7) * 32, tr = (bb >> 3) * 32;
    int lx = threadIdx.x & 31, ly = threadIdx.x >> 5;
#pragma unroll
    for (int i = 0; i < 32; i += 8)
      tile[ly + i][lx] = in[(size_t)(tr + ly + i) * 256 + tc + lx];
    __syncthreads();
#pragma unroll
    for (int i = 0; i < 32; i += 8)
      outp[(size_t)(tc + ly + i) * 1024 + tr + lx] = f2bf(tile[lx][ly + i]);
    return;
  }
  else if (b < 6304) { pack_seg(pW1, uW1, W1pk, b - 6272); return; }
  else if (b < 6336) { pack_seg(pW2, uW2, W2pk, b - 6304); return; }
  else {
    int w = threadIdx.x >> 6, lane = threadIdx.x & 63;
    int row = (b - 6336) * 4 + w;
    int br = row >> 9, n = row & 511;
    const float* Kr = (br ? Kp : Kc) + (size_t)n * PP;
    const float* bf = br ? bfp : bfc;
    float s = 0.f;
#pragma unroll
    for (int j = 0; j < 12; ++j) s += Kr[lane + j * 64] * bf[lane + j * 64];
#pragma unroll
    for (int o = 32; o; o >>= 1) s += __shfl_xor(s, o);
    if (!lane) sb[row] = s;
  }
}

// ---------------------------------------------------------------------------
// merged small GEMMs (all 64x64 tiles): [0,192) = KW; [192,256) = VW1
// ---------------------------------------------------------------------------
__global__ __launch_bounds__(256) void gemm_mixed(
    const u16* Kcb, const u16* Kpb, const u16* Wfcb, const u16* Wfpb,
    u16* KWc, u16* KWp,
    const u16* W1Tp, const u16* W1Tu, const u16* Vcb, const u16* Vpb,
    u16* VW1p, u16* VW1u)
{
  __shared__ u16 lsA[64 * 64];
  __shared__ u16 lsB[64 * 64];
  int b = blockIdx.x;
  if (b < 192) {
    int z = b / 96, r = b % 96;
    gemm_core6464<2>(z ? Kpb : Kcb, PP, z ? Wfpb : Wfcb, PP, nullptr,
                     z ? KWp : KWc, PP, PP, (r & 7) * 64, (r >> 3) * 64, lsA, lsB);
  } else {
    int c = b - 192, z = c / 32, r = c % 32;
    gemm_core6464<2>((z ? W1Tu : W1Tp) + 256, 1024, z ? Vpb : Vcb, PP, nullptr,
                     z ? VW1u : VW1p, NC, PP, (r & 3) * 64, (r >> 2) * 64, lsA, lsB);
  }
}

// scores = instb @ [KWc;KWp]^T + sb -> f16 [4096][1024]; grid (1024) swizzled
__global__ __launch_bounds__(256) void gemm_scores(
    const u16* instb, const u16* KW, const float* sb, u16* scH)
{
  __shared__ u16 lsA[64 * 64];
  __shared__ u16 lsB[64 * 64];
  int b = xcd_swz(blockIdx.x, 1024);
  int bx = b & 63, by = b >> 6;
  gemm_core6464<5>(instb, PP, KW, PP, sb, scH, 1024, PP,
                   bx * 64, by * 64, lsA, lsB);
}

// t = P @ VW1 + b1 -> bf16 [2][4096][256]; grid (64, 4, 2)
__global__ __launch_bounds__(256) void gemm_t(
    const u16* Pb, const u16* VW1p, const u16* VW1u,
    const float* pb1, const float* ub1, u16* t0, u16* t1)
{
  __shared__ u16 lsA[64 * 64];
  __shared__ u16 lsB[64 * 64];
  int z = blockIdx.z;
  gemm_core6464<6>(Pb + (size_t)z * BB * NC, NC, z ? VW1u : VW1p, NC,
                   z ? ub1 : pb1, z ? t1 : t0, SLOT, NC,
                   blockIdx.x * 64, blockIdx.y * 64, lsA, lsB);
}

// ---------------------------------------------------------------------------
// softmax over rows of 512; input f16 logits (sb folded); alpha folded  [R12]
// ---------------------------------------------------------------------------
__global__ __launch_bounds__(256) void softmax_rows(const u16* __restrict__ scH,
                                                    u16* __restrict__ Pp) {
  int w = threadIdx.x >> 6, lane = threadIdx.x & 63;
  int row = blockIdx.x * 4 + w;
  int i = row >> 1, b = row & 1;
  const u16* src = scH + (size_t)i * 1024 + b * 512 + lane * 8;
  uint4 q = *(const uint4*)src;
  const u16* hp = (const u16*)&q;
  float vv[8];
#pragma unroll
  for (int j = 0; j < 8; ++j) vv[j] = h2f(hp[j]);
  float m = vv[0];
#pragma unroll
  for (int j = 1; j < 8; ++j) m = fmaxf(m, vv[j]);
#pragma unroll
  for (int o = 32; o; o >>= 1) m = fmaxf(m, __shfl_xor(m, o));
  const float alpha = 0.03608439182435161f;   // 1/sqrt(768)
  float e[8], s = 0.f;
#pragma unroll
  for (int j = 0; j < 8; ++j) { e[j] = __expf((vv[j] - m) * alpha); s += e[j]; }
#pragma unroll
  for (int o = 32; o; o >>= 1) s += __shfl_xor(s, o);
  float inv = 1.f / s;
  union { u16 u[8]; uint4 q; } ou;
#pragma unroll
  for (int j = 0; j < 8; ++j) ou.u[j] = f2bf(e[j] * inv);
  *(uint4*)(Pp + ((size_t)b * BB + i) * 512 + lane * 8) = ou.q;
}

// ---------------------------------------------------------------------------
// FUSED back half (R17 verified ~44-46us) + XCD-aware block swizzle (T1).
// ---------------------------------------------------------------------------
__global__ __launch_bounds__(512, 4) void fused_update(
    const float* __restrict__ slots,
    const u16* __restrict__ t0, const u16* __restrict__ t1,
    const u16* __restrict__ W1pk, const u16* __restrict__ W2pk,
    const float* __restrict__ pg, const float* __restrict__ pbt,
    const float* __restrict__ ug, const float* __restrict__ ubt,
    const float* __restrict__ pb2, const float* __restrict__ ub2,
    float* __restrict__ outp)
{
  __shared__ u16 lsH[2][32 * 256];
  __shared__ float lstat[2][32][16];
  __shared__ float lfin[2][32][2];

  const int tid = threadIdx.x, w = tid >> 6, lane = tid & 63;
  const int rl = lane >> 4, cl = lane & 15;
  const int bidx = xcd_swz(blockIdx.x, 1024);
  const int blockRow = bidx * 32;

  u16* lsA = lsH[0];

#pragma unroll
  for (int it = 0; it < 4; ++it) {
    int L = it * 512 + tid;
    int row = L >> 6, qc = L & 63;
    float4 v = *(const float4*)(slots + (size_t)(blockRow + row) * 256 + qc * 4);
    ushort4 b; b.x = f2bf(v.x); b.y = f2bf(v.y); b.z = f2bf(v.z); b.w = f2bf(v.w);
    int chunk = qc >> 1, half = qc & 1;
    *(ushort4*)(lsA + row * 256 + (((chunk ^ (row & 7)) << 3) + half * 4)) = b;
  }

  float tp_[2][2], tu_[2][2];
#pragma unroll
  for (int fm = 0; fm < 2; ++fm) {
    size_t trr = (size_t)(bidx * 4 + fm * 2 + (rl >> 1)) * 256;
#pragma unroll
    for (int fn = 0; fn < 2; ++fn) {
      int col = w * 32 + fn * 16 + cl;
      tp_[fm][fn] = bf2f(t0[trr + col]);
      tu_[fm][fn] = bf2f(t1[trr + col]);
    }
  }

#define MF(A, B, C) C = __builtin_amdgcn_mfma_f32_16x16x32_bf16(A, B, C, 0, 0, 0);

  bf16x8 pb[3][2], ub[3][2];
#define FR1(NG, S) (*(const bf16x8*)(W1pk + (size_t)(((NG) * 8 + (S)) * 64 + lane) * 8))
#define LDW1(SL, S) { pb[SL][0] = FR1(w * 2, S);      pb[SL][1] = FR1(w * 2 + 1, S);  \
                      ub[SL][0] = FR1(16 + w * 2, S); ub[SL][1] = FR1(17 + w * 2, S); \
                      asm volatile("" ::: "memory"); }
  LDW1(0, 0) LDW1(1, 1) LDW1(2, 2)
  __syncthreads();                                   // B1

  f32x4 acc[2][4];
  const f32x4 zero = {0.f, 0.f, 0.f, 0.f};
#pragma unroll
  for (int i = 0; i < 2; ++i)
#pragma unroll
    for (int j = 0; j < 4; ++j) acc[i][j] = zero;

  __builtin_amdgcn_s_setprio(1);
#pragma unroll
  for (int s = 0; s < 8; ++s) {
    const int sl = s % 3;
    bf16x8 a0 = *(const bf16x8*)(lsA + cl * 256 + (((s * 4 + rl) ^ (cl & 7)) << 3));
    bf16x8 a1 = *(const bf16x8*)(lsA + (16 + cl) * 256 + (((s * 4 + rl) ^ (cl & 7)) << 3));
    MF(a0, pb[sl][0], acc[0][0]) MF(a1, pb[sl][0], acc[1][0])
    MF(a0, pb[sl][1], acc[0][1]) MF(a1, pb[sl][1], acc[1][1])
    MF(a0, ub[sl][0], acc[0][2]) MF(a1, ub[sl][0], acc[1][2])
    MF(a0, ub[sl][1], acc[0][3]) MF(a1, ub[sl][1], acc[1][3])
    if (s < 5) LDW1(sl, s + 3)
  }
  __builtin_amdgcn_s_setprio(0);
#undef LDW1
#undef FR1

#pragma unroll
  for (int fm = 0; fm < 2; ++fm)
#pragma unroll
    for (int fn = 0; fn < 2; ++fn)
#pragma unroll
      for (int r = 0; r < 4; ++r) {
        acc[fm][fn][r]     += tp_[fm][fn];
        acc[fm][2 + fn][r] += tu_[fm][fn];
      }

#pragma unroll
  for (int fm = 0; fm < 2; ++fm)
#pragma unroll
    for (int br = 0; br < 2; ++br) {
      f32x4 s = acc[fm][br * 2] + acc[fm][br * 2 + 1];
      f32x4 q = acc[fm][br * 2] * acc[fm][br * 2] + acc[fm][br * 2 + 1] * acc[fm][br * 2 + 1];
#pragma unroll
      for (int o = 1; o < 16; o <<= 1) {
#pragma unroll
        for (int r = 0; r < 4; ++r) {
          s[r] += __shfl_xor(s[r], o);
          q[r] += __shfl_xor(q[r], o);
        }
      }
      if (cl == 0) {
#pragma unroll
        for (int r = 0; r < 4; ++r) {
          int row = fm * 16 + rl * 4 + r;
          lstat[br][row][w]     = s[r];
          lstat[br][row][8 + w] = q[r];
        }
      }
    }
  __syncthreads();                                   // B2

  if (tid < 64) {
    int fb = tid >> 5, row = tid & 31;
    f32x4 a = *(const f32x4*)&lstat[fb][row][0];
    f32x4 b = *(const f32x4*)&lstat[fb][row][4];
    f32x4 c = *(const f32x4*)&lstat[fb][row][8];
    f32x4 d = *(const f32x4*)&lstat[fb][row][12];
    float ss = a[0] + a[1] + a[2] + a[3] + b[0] + b[1] + b[2] + b[3];
    float qq = c[0] + c[1] + c[2] + c[3] + d[0] + d[1] + d[2] + d[3];
    float mu = ss * (1.f / 256.f);
    lfin[fb][row][0] = mu;
    lfin[fb][row][1] = rsqrtf(qq * (1.f / 256.f) - mu * mu + 1e-5f);
  }
  __syncthreads();                                   // B2b

  const int brw = w >> 2, wc = w & 3;
  const u16* hsrc = lsH[brw];
  const float* b2src = brw ? ub2 : pb2;
  float b2v[4];
#pragma unroll
  for (int fn = 0; fn < 4; ++fn) b2v[fn] = b2src[wc * 64 + fn * 16 + cl];

  bf16x8 bq[3][4];
#define FR2(NG, S) (*(const bf16x8*)(W2pk + (size_t)(((NG) * 8 + (S)) * 64 + lane) * 8))
#define LDW2(SL, S) { bq[SL][0] = FR2(brw * 16 + wc * 4,     S); \
                      bq[SL][1] = FR2(brw * 16 + wc * 4 + 1, S); \
                      bq[SL][2] = FR2(brw * 16 + wc * 4 + 2, S); \
                      bq[SL][3] = FR2(brw * 16 + wc * 4 + 3, S); \
                      asm volatile("" ::: "memory"); }
  LDW2(0, 0)

  {
    float gv[2][2], btv[2][2];
#pragma unroll
    for (int fn = 0; fn < 2; ++fn) {
      int col = w * 32 + fn * 16 + cl;
      gv[0][fn] = pg[col];  btv[0][fn] = pbt[col];
      gv[1][fn] = ug[col];  btv[1][fn] = ubt[col];
    }
#pragma unroll
    for (int fm = 0; fm < 2; ++fm) {
      float mean[2][4], rstd[2][4];
#pragma unroll
      for (int r = 0; r < 4; ++r) {
        int row = fm * 16 + rl * 4 + r;
        mean[0][r] = lfin[0][row][0]; rstd[0][r] = lfin[0][row][1];
        mean[1][r] = lfin[1][row][0]; rstd[1][r] = lfin[1][row][1];
      }
#pragma unroll
      for (int br = 0; br < 2; ++br)
#pragma unroll
        for (int fn = 0; fn < 2; ++fn) {
          int col = w * 32 + fn * 16 + cl;
#pragma unroll
          for (int r = 0; r < 4; ++r) {
            int row = fm * 16 + rl * 4 + r;
            float h = fmaxf((acc[fm][br * 2 + fn][r] - mean[br][r]) * rstd[br][r]
                            * gv[br][fn] + btv[br][fn], 0.f);
            lsH[br][row * 256 + (((col >> 3) ^ (row & 7)) << 3) + (col & 7)] = f2bf(h);
          }
        }
    }
  }
#pragma unroll
  for (int i = 0; i < 2; ++i)
#pragma unroll
    for (int j = 0; j < 4; ++j) acc[i][j] = zero;
  __syncthreads();                                   // B3

  LDW2(1, 1) LDW2(2, 2)
  __builtin_amdgcn_s_setprio(1);
#pragma unroll
  for (int s = 0; s < 8; ++s) {
    const int sl = s % 3;
    bf16x8 a0 = *(const bf16x8*)(hsrc + cl * 256 + (((s * 4 + rl) ^ (cl & 7)) << 3));
    bf16x8 a1 = *(const bf16x8*)(hsrc + (16 + cl) * 256 + (((s * 4 + rl) ^ (cl & 7)) << 3));
    MF(a0, bq[sl][0], acc[0][0]) MF(a1, bq[sl][0], acc[1][0])
    MF(a0, bq[sl][1], acc[0][1]) MF(a1, bq[sl][1], acc[1][1])
    MF(a0, bq[sl][2], acc[0][2]) MF(a1, bq[sl][2], acc[1][2])
    MF(a0, bq[sl][3], acc[0][3]) MF(a1, bq[sl][3], acc[1][3])
    if (s < 5) LDW2(sl, s + 3)
  }
  __builtin_amdgcn_s_setprio(0);
#undef LDW2
#undef FR2
#undef MF
  __syncthreads();                                   // B4

  float* xbuf = (float*)&lsH[0][0];
  const int base = wc * 2048;
  if (brw == 0) {
#pragma unroll
    for (int fm = 0; fm < 2; ++fm)
#pragma unroll
      for (int fn = 0; fn < 4; ++fn)
#pragma unroll
        for (int r = 0; r < 4; ++r)
          xbuf[base + ((fm * 4 + fn) * 4 + r) * 64 + lane] = acc[fm][fn][r] + b2v[fn];
  }
  __syncthreads();                                   // B5

  if (brw == 1) {
#pragma unroll
    for (int fm = 0; fm < 2; ++fm)
#pragma unroll
      for (int fn = 0; fn < 4; ++fn)
#pragma unroll
        for (int r = 0; r < 4; ++r) {
          float gp = xbuf[base + ((fm * 4 + fn) * 4 + r) * 64 + lane];
          float gu = acc[fm][fn][r] + b2v[fn];
          int row = blockRow + fm * 16 + rl * 4 + r;
          int col = wc * 64 + fn * 16 + cl;
          size_t idx = (size_t)row * 256 + col;
          outp[idx] = slots[idx] + gp * gu;
        }
  }
}

// ---------------------------------------------------------------------------
// host launcher
// ---------------------------------------------------------------------------
extern "C" void kernel_launch(void* const* d_in, const int* in_sizes, int n_in,
                              void* d_out, int out_size, void* d_ws, size_t ws_size,
                              hipStream_t stream) {
  const float* inst  = (const float*)d_in[0];
  const float* slots = (const float*)d_in[1];
  const float* Wfc   = (const float*)d_in[2];
  const float* bfc   = (const float*)d_in[3];
  const float* Wfp   = (const float*)d_in[4];
  const float* bfp   = (const float*)d_in[5];
  const float* Kc    = (const float*)d_in[6];
  const float* Vc    = (const float*)d_in[7];
  const float* Kp    = (const float*)d_in[8];
  const float* Vp    = (const float*)d_in[9];
  const float* pW1   = (const float*)d_in[10];
  const float* pb1   = (const float*)d_in[11];
  const float* pg    = (const float*)d_in[12];
  const float* pbt   = (const float*)d_in[13];
  const float* pW2   = (const float*)d_in[14];
  const float* pb2   = (const float*)d_in[15];
  const float* uW1   = (const float*)d_in[16];
  const float* ub1   = (const float*)d_in[17];
  const float* ug    = (const float*)d_in[18];
  const float* ubt   = (const float*)d_in[19];
  const float* uW2   = (const float*)d_in[20];
  const float* ub2   = (const float*)d_in[21];
  float* out = (float*)d_out;
  char*  ws  = (char*)d_ws;

  const size_t OFF_INST  = 0;
  const size_t OFF_KC    = OFF_INST  + 6291456;
  const size_t OFF_KP    = OFF_KC    + 786432;
  const size_t OFF_WFCB  = OFF_KP    + 786432;
  const size_t OFF_WFPB  = OFF_WFCB  + 1179648;
  const size_t OFF_VCB   = OFF_WFPB  + 1179648;
  const size_t OFF_VPB   = OFF_VCB   + 786432;
  const size_t OFF_W1TP  = OFF_VPB   + 786432;
  const size_t OFF_W1TU  = OFF_W1TP  + 524288;
  const size_t OFF_W1PK  = OFF_W1TU  + 524288;
  const size_t OFF_W2PK  = OFF_W1PK  + 262144;
  const size_t OFF_KW    = OFF_W2PK  + 262144;
  const size_t OFF_VW1   = OFF_KW    + 1572864;
  const size_t OFF_SB    = OFF_VW1   + 524288;
  const size_t OFF_T     = OFF_SB    + 4096;          // [2][4096][256] bf16
  const size_t OFF_SC    = OFF_T     + 4194304;
  const size_t OFF_P     = OFF_SC    + 8388608;

  u16*   instb = (u16*)(ws + OFF_INST);
  u16*   Kcb   = (u16*)(ws + OFF_KC);
  u16*   Kpb   = (u16*)(ws + OFF_KP);
  u16*   Wfcb  = (u16*)(ws + OFF_WFCB);
  u16*   Wfpb  = (u16*)(ws + OFF_WFPB);
  u16*   Vcb   = (u16*)(ws + OFF_VCB);
  u16*   Vpb   = (u16*)(ws + OFF_VPB);
  u16*   W1Tp  = (u16*)(ws + OFF_W1TP);
  u16*   W1Tu  = (u16*)(ws + OFF_W1TU);
  u16*   W1pk  = (u16*)(ws + OFF_W1PK);
  u16*   W2pk  = (u16*)(ws + OFF_W2PK);
  u16*   KWc   = (u16*)(ws + OFF_KW);
  u16*   KWp   = KWc + (size_t)NC * PP;
  u16*   VW1p  = (u16*)(ws + OFF_VW1);
  u16*   VW1u  = VW1p + (size_t)SLOT * NC;
  float* sb    = (float*)(ws + OFF_SB);
  u16*   t0    = (u16*)(ws + OFF_T);
  u16*   t1    = t0 + (size_t)BB * SLOT;
  u16*   scH   = (u16*)(ws + OFF_SC);
  u16*   Pb    = (u16*)(ws + OFF_P);

  prep_all<<<dim3(6592), 256, 0, stream>>>(
      inst, Kc, Kp, Wfc, Wfp, Vc, Vp, pW1, uW1, pW2, uW2, bfc, bfp,
      instb, Kcb, Kpb, Wfcb, Wfpb, Vcb, Vpb, W1Tp, W1Tu, W1pk, W2pk, sb);

  gemm_mixed<<<dim3(256), 256, 0, stream>>>(
      Kcb, Kpb, Wfcb, Wfpb, KWc, KWp, W1Tp, W1Tu, Vcb, Vpb, VW1p, VW1u);

  gemm_scores<<<dim3(1024), 256, 0, stream>>>(instb, KWc, sb, scH);

  softmax_rows<<<dim3(2048), 256, 0, stream>>>(scH, Pb);

  gemm_t<<<dim3(64, 4, 2), 256, 0, stream>>>(Pb, VW1p, VW1u, pb1, ub1, t0, t1);

  fused_update<<<dim3(1024), 512, 0, stream>>>(
      slots, t0, t1, W1pk, W2pk, pg, pbt, ug, ubt, pb2, ub2, out);

  (void)in_sizes; (void)n_in; (void)out_size; (void)ws_size;
}

// Round 19
// 83.541 us; speedup vs baseline: 1.0299x; 1.0299x over previous
//
#include <hip/hip_runtime.h>
#include <stdint.h>

#define BB    4096
#define KS    8
#define PP    768
#define SLOT  256
#define HID   256
#define NC    512
#define BKROWS (BB*KS)          // 32768
typedef unsigned short u16;
typedef short bf16x8 __attribute__((ext_vector_type(8)));
typedef float f32x4  __attribute__((ext_vector_type(4)));

__device__ __forceinline__ u16 f2bf(float x) {
  union { float f; uint32_t u; } v; v.f = x;
  return (u16)((v.u + 0x7FFFu + ((v.u >> 16) & 1u)) >> 16);
}
__device__ __forceinline__ float bf2f(u16 x) {
  union { uint32_t u; float f; } v; v.u = (uint32_t)x << 16; return v.f;
}
__device__ __forceinline__ u16 f2h(float x) {
  union { _Float16 h; u16 u; } cv; cv.h = (_Float16)x; return cv.u;
}
__device__ __forceinline__ float h2f(u16 x) {
  union { u16 u; _Float16 h; } cv; cv.u = x; return (float)cv.h;
}

__device__ __forceinline__ void gload_lds16(u16* ldst, const u16* gsrc) {
  __builtin_amdgcn_global_load_lds(
      (const __attribute__((address_space(1))) void*)gsrc,
      (__attribute__((address_space(3))) void*)ldst, 16, 0, 0);
}

// ---------------------------------------------------------------------------
// GEMM core 64x64: BM=BN=64, BK=64, 4 waves (2Mx2N), wave 32x32. acc 16 regs.
// EPI: 2 = bf16; 3 = +bias f32; 5 = +bias f16; 6 = +bias bf16.  [R12-verified]
// ---------------------------------------------------------------------------
template<int EPI>
__device__ __forceinline__ void gemm_core6464(
    const u16* __restrict__ A, int lda,
    const u16* __restrict__ B, int ldb,
    const float* __restrict__ bias,
    void* __restrict__ out, int ldo, int K,
    int blockRow, int blockCol, u16* lsA, u16* lsB)
{
  const int tid  = threadIdx.x;
  const int w    = tid >> 6;
  const int lane = tid & 63;
  const int wm   = w >> 1, wn = w & 1;
  const int rl   = lane >> 4, cl = lane & 15;

  f32x4 acc[2][2];
  const f32x4 zero = {0.f, 0.f, 0.f, 0.f};
#pragma unroll
  for (int i = 0; i < 2; ++i)
#pragma unroll
    for (int j = 0; j < 2; ++j) acc[i][j] = zero;

  const u16* Ablk = A + (size_t)blockRow * lda;
  const u16* Bblk = B + (size_t)blockCol * ldb;

  for (int k0 = 0; k0 < K; k0 += 64) {
#pragma unroll
    for (int i = 0; i < 2; ++i) {
      int seg   = i * 4 + w;
      int off16 = seg * 64 + lane;
      int row   = off16 >> 3;
      int chunk = (off16 & 7) ^ (row & 7);
      gload_lds16(lsA + seg * 512, Ablk + (size_t)row * lda + k0 + chunk * 8);
    }
#pragma unroll
    for (int i = 0; i < 2; ++i) {
      int seg   = i * 4 + w;
      int off16 = seg * 64 + lane;
      int row   = off16 >> 3;
      int chunk = (off16 & 7) ^ (row & 7);
      gload_lds16(lsB + seg * 512, Bblk + (size_t)row * ldb + k0 + chunk * 8);
    }
    __syncthreads();

#pragma unroll
    for (int ks = 0; ks < 2; ++ks) {
      bf16x8 aF[2], bF[2];
#pragma unroll
      for (int f = 0; f < 2; ++f) {
        int r  = wm * 32 + f * 16 + cl;
        int ca = ((ks * 4 + rl) ^ (r & 7)) * 8;
        aF[f] = *(const bf16x8*)(lsA + r * 64 + ca);
        int rn = wn * 32 + f * 16 + cl;
        int cb = ((ks * 4 + rl) ^ (rn & 7)) * 8;
        bF[f] = *(const bf16x8*)(lsB + rn * 64 + cb);
      }
#pragma unroll
      for (int fm = 0; fm < 2; ++fm)
#pragma unroll
        for (int fn = 0; fn < 2; ++fn)
          acc[fm][fn] = __builtin_amdgcn_mfma_f32_16x16x32_bf16(
              aF[fm], bF[fn], acc[fm][fn], 0, 0, 0);
    }
    __syncthreads();
  }

#pragma unroll
  for (int fm = 0; fm < 2; ++fm) {
#pragma unroll
    for (int fn = 0; fn < 2; ++fn) {
      f32x4 v = acc[fm][fn];
#pragma unroll
      for (int r = 0; r < 4; ++r) {
        int grow = blockRow + wm * 32 + fm * 16 + rl * 4 + r;
        int gcol = blockCol + wn * 32 + fn * 16 + cl;
        float x = v[r];
        if constexpr (EPI == 2) {
          ((u16*)out)[(size_t)grow * ldo + gcol] = f2bf(x);
        } else if constexpr (EPI == 3) {
          x += bias[gcol];
          ((float*)out)[(size_t)grow * ldo + gcol] = x;
        } else if constexpr (EPI == 5) {
          x += bias[gcol];
          ((u16*)out)[(size_t)grow * ldo + gcol] = f2h(x);
        } else if constexpr (EPI == 6) {
          x += bias[gcol];
          ((u16*)out)[(size_t)grow * ldo + gcol] = f2bf(x);
        }
      }
    }
  }
}

// ---------------------------------------------------------------------------
// prep_all (R12 layout)
// ---------------------------------------------------------------------------
__device__ __forceinline__ void cvt_seg(const float* __restrict__ in,
                                        u16* __restrict__ outp, int b, int n4) {
  int i = b * 256 + threadIdx.x;
  if (i < n4) {
    float4 v = ((const float4*)in)[i];
    ushort4 o;
    o.x = f2bf(v.x); o.y = f2bf(v.y); o.z = f2bf(v.z); o.w = f2bf(v.w);
    ((ushort4*)outp)[i] = o;
  }
}

__device__ __forceinline__ void pack_seg(const float* __restrict__ s0,
                                         const float* __restrict__ s1,
                                         u16* __restrict__ dst, int b) {
  int br = b >> 4, ng = b & 15;
  const float* src = br ? s1 : s0;
  int w = threadIdx.x >> 6, lane = threadIdx.x & 63;
  int rl = lane >> 4, cl = lane & 15;
#pragma unroll
  for (int s = 0; s < 2; ++s) {
    int step = w * 2 + s;
    union { u16 u[8]; uint4 q; } o;
#pragma unroll
    for (int j = 0; j < 8; ++j)
      o.u[j] = f2bf(src[(size_t)(step * 32 + rl * 8 + j) * 256 + ng * 16 + cl]);
    *(uint4*)(dst + (size_t)(((br * 16 + ng) * 8 + step) * 64 + lane) * 8) = o.q;
  }
}

__global__ __launch_bounds__(256) void prep_all(
    const float* __restrict__ inst, const float* __restrict__ Kc,
    const float* __restrict__ Kp, const float* __restrict__ Wfc,
    const float* __restrict__ Wfp, const float* __restrict__ Vc,
    const float* __restrict__ Vp, const float* __restrict__ pW1,
    const float* __restrict__ uW1, const float* __restrict__ pW2,
    const float* __restrict__ uW2, const float* __restrict__ bfc,
    const float* __restrict__ bfp,
    u16* instb, u16* Kcb, u16* Kpb, u16* Wfcb, u16* Wfpb, u16* Vcb, u16* Vpb,
    u16* W1Tp, u16* W1Tu, u16* W1pk, u16* W2pk, float* sb)
{
  __shared__ float tile[32][33];
  int b = blockIdx.x;
  if (b < 3072)      { cvt_seg(inst, instb, b,        786432); return; }
  else if (b < 3456) { cvt_seg(Kc,   Kcb,   b - 3072,  98304); return; }
  else if (b < 3840) { cvt_seg(Kp,   Kpb,   b - 3456,  98304); return; }
  else if (b < 4416) { cvt_seg(Wfc,  Wfcb,  b - 3840, 147456); return; }
  else if (b < 4992) { cvt_seg(Wfp,  Wfpb,  b - 4416, 147456); return; }
  else if (b < 5376) { cvt_seg(Vc,   Vcb,   b - 4992,  98304); return; }
  else if (b < 5760) { cvt_seg(Vp,   Vpb,   b - 5376,  98304); return; }
  else if (b < 6272) {
    int bb = b - 5760;
    const float* in = (bb < 256) ? pW1 : uW1;
    u16* outp = (bb < 256) ? W1Tp : W1Tu;
    bb &= 255;
    int tc = (bb & 7) * 32, tr = (bb >> 3) * 32;
    int lx = threadIdx.x & 31, ly = threadIdx.x >> 5;
#pragma unroll
    for (int i = 0; i < 32; i += 8)
      tile[ly + i][lx] = in[(size_t)(tr + ly + i) * 256 + tc + lx];
    __syncthreads();
#pragma unroll
    for (int i = 0; i < 32; i += 8)
      outp[(size_t)(tc + ly + i) * 1024 + tr + lx] = f2bf(tile[lx][ly + i]);
    return;
  }
  else if (b < 6304) { pack_seg(pW1, uW1, W1pk, b - 6272); return; }
  else if (b < 6336) { pack_seg(pW2, uW2, W2pk, b - 6304); return; }
  else {
    int w = threadIdx.x >> 6, lane = threadIdx.x & 63;
    int row = (b - 6336) * 4 + w;
    int br = row >> 9, n = row & 511;
    const float* Kr = (br ? Kp : Kc) + (size_t)n * PP;
    const float* bf = br ? bfp : bfc;
    float s = 0.f;
#pragma unroll
    for (int j = 0; j < 12; ++j) s += Kr[lane + j * 64] * bf[lane + j * 64];
#pragma unroll
    for (int o = 32; o; o >>= 1) s += __shfl_xor(s, o);
    if (!lane) sb[row] = s;
  }
}

// ---------------------------------------------------------------------------
// merged small GEMMs (all 64x64 tiles): [0,192) = KW; [192,256) = VW1
// ---------------------------------------------------------------------------
__global__ __launch_bounds__(256) void gemm_mixed(
    const u16* Kcb, const u16* Kpb, const u16* Wfcb, const u16* Wfpb,
    u16* KWc, u16* KWp,
    const u16* W1Tp, const u16* W1Tu, const u16* Vcb, const u16* Vpb,
    u16* VW1p, u16* VW1u)
{
  __shared__ u16 lsA[64 * 64];
  __shared__ u16 lsB[64 * 64];
  int b = blockIdx.x;
  if (b < 192) {
    int z = b / 96, r = b % 96;
    gemm_core6464<2>(z ? Kpb : Kcb, PP, z ? Wfpb : Wfcb, PP, nullptr,
                     z ? KWp : KWc, PP, PP, (r & 7) * 64, (r >> 3) * 64, lsA, lsB);
  } else {
    int c = b - 192, z = c / 32, r = c % 32;
    gemm_core6464<2>((z ? W1Tu : W1Tp) + 256, 1024, z ? Vpb : Vcb, PP, nullptr,
                     z ? VW1u : VW1p, NC, PP, (r & 3) * 64, (r >> 2) * 64, lsA, lsB);
  }
}

// scores = instb @ [KWc;KWp]^T + sb -> f16 [4096][1024]; grid (64,16)
__global__ __launch_bounds__(256) void gemm_scores(
    const u16* instb, const u16* KW, const float* sb, u16* scH)
{
  __shared__ u16 lsA[64 * 64];
  __shared__ u16 lsB[64 * 64];
  gemm_core6464<5>(instb, PP, KW, PP, sb, scH, 1024, PP,
                   blockIdx.x * 64, blockIdx.y * 64, lsA, lsB);
}

// t = P @ VW1 + b1 -> bf16 [2][4096][256]; grid (64, 4, 2)
__global__ __launch_bounds__(256) void gemm_t(
    const u16* Pb, const u16* VW1p, const u16* VW1u,
    const float* pb1, const float* ub1, u16* t0, u16* t1)
{
  __shared__ u16 lsA[64 * 64];
  __shared__ u16 lsB[64 * 64];
  int z = blockIdx.z;
  gemm_core6464<6>(Pb + (size_t)z * BB * NC, NC, z ? VW1u : VW1p, NC,
                   z ? ub1 : pb1, z ? t1 : t0, SLOT, NC,
                   blockIdx.x * 64, blockIdx.y * 64, lsA, lsB);
}

// ---------------------------------------------------------------------------
// softmax over rows of 512; input f16 logits (sb folded); alpha folded
// ---------------------------------------------------------------------------
__global__ __launch_bounds__(256) void softmax_rows(const u16* __restrict__ scH,
                                                    u16* __restrict__ Pp) {
  int w = threadIdx.x >> 6, lane = threadIdx.x & 63;
  int row = blockIdx.x * 4 + w;
  int i = row >> 1, b = row & 1;
  const u16* src = scH + (size_t)i * 1024 + b * 512 + lane * 8;
  uint4 q = *(const uint4*)src;
  const u16* hp = (const u16*)&q;
  float vv[8];
#pragma unroll
  for (int j = 0; j < 8; ++j) vv[j] = h2f(hp[j]);
  float m = vv[0];
#pragma unroll
  for (int j = 1; j < 8; ++j) m = fmaxf(m, vv[j]);
#pragma unroll
  for (int o = 32; o; o >>= 1) m = fmaxf(m, __shfl_xor(m, o));
  const float alpha = 0.03608439182435161f;   // 1/sqrt(768)
  float e[8], s = 0.f;
#pragma unroll
  for (int j = 0; j < 8; ++j) { e[j] = __expf((vv[j] - m) * alpha); s += e[j]; }
#pragma unroll
  for (int o = 32; o; o >>= 1) s += __shfl_xor(s, o);
  float inv = 1.f / s;
  union { u16 u[8]; uint4 q; } ou;
#pragma unroll
  for (int j = 0; j < 8; ++j) ou.u[j] = f2bf(e[j] * inv);
  *(uint4*)(Pp + ((size_t)b * BB + i) * 512 + lane * 8) = ou.q;
}

// ---------------------------------------------------------------------------
// FUSED back half (R17 verified, best measured): branch-split GEMM2 + LDS
// xchg; hoisted t-loads (bf16) + LDW1 prologue before B1; LDW2(0) under
// normalize; setprio around MFMA loops.
// ---------------------------------------------------------------------------
__global__ __launch_bounds__(512, 4) void fused_update(
    const float* __restrict__ slots,
    const u16* __restrict__ t0, const u16* __restrict__ t1,
    const u16* __restrict__ W1pk, const u16* __restrict__ W2pk,
    const float* __restrict__ pg, const float* __restrict__ pbt,
    const float* __restrict__ ug, const float* __restrict__ ubt,
    const float* __restrict__ pb2, const float* __restrict__ ub2,
    float* __restrict__ outp)
{
  __shared__ u16 lsH[2][32 * 256];
  __shared__ float lstat[2][32][16];
  __shared__ float lfin[2][32][2];

  const int tid = threadIdx.x, w = tid >> 6, lane = tid & 63;
  const int rl = lane >> 4, cl = lane & 15;
  const int blockRow = blockIdx.x * 32;

  u16* lsA = lsH[0];

#pragma unroll
  for (int it = 0; it < 4; ++it) {
    int L = it * 512 + tid;
    int row = L >> 6, qc = L & 63;
    float4 v = *(const float4*)(slots + (size_t)(blockRow + row) * 256 + qc * 4);
    ushort4 b; b.x = f2bf(v.x); b.y = f2bf(v.y); b.z = f2bf(v.z); b.w = f2bf(v.w);
    int chunk = qc >> 1, half = qc & 1;
    *(ushort4*)(lsA + row * 256 + (((chunk ^ (row & 7)) << 3) + half * 4)) = b;
  }

  float tp_[2][2], tu_[2][2];
#pragma unroll
  for (int fm = 0; fm < 2; ++fm) {
    size_t trr = (size_t)(blockIdx.x * 4 + fm * 2 + (rl >> 1)) * 256;
#pragma unroll
    for (int fn = 0; fn < 2; ++fn) {
      int col = w * 32 + fn * 16 + cl;
      tp_[fm][fn] = bf2f(t0[trr + col]);
      tu_[fm][fn] = bf2f(t1[trr + col]);
    }
  }

#define MF(A, B, C) C = __builtin_amdgcn_mfma_f32_16x16x32_bf16(A, B, C, 0, 0, 0);

  bf16x8 pb[3][2], ub[3][2];
#define FR1(NG, S) (*(const bf16x8*)(W1pk + (size_t)(((NG) * 8 + (S)) * 64 + lane) * 8))
#define LDW1(SL, S) { pb[SL][0] = FR1(w * 2, S);      pb[SL][1] = FR1(w * 2 + 1, S);  \
                      ub[SL][0] = FR1(16 + w * 2, S); ub[SL][1] = FR1(17 + w * 2, S); \
                      asm volatile("" ::: "memory"); }
  LDW1(0, 0) LDW1(1, 1) LDW1(2, 2)
  __syncthreads();                                   // B1

  f32x4 acc[2][4];
  const f32x4 zero = {0.f, 0.f, 0.f, 0.f};
#pragma unroll
  for (int i = 0; i < 2; ++i)
#pragma unroll
    for (int j = 0; j < 4; ++j) acc[i][j] = zero;

  __builtin_amdgcn_s_setprio(1);
#pragma unroll
  for (int s = 0; s < 8; ++s) {
    const int sl = s % 3;
    bf16x8 a0 = *(const bf16x8*)(lsA + cl * 256 + (((s * 4 + rl) ^ (cl & 7)) << 3));
    bf16x8 a1 = *(const bf16x8*)(lsA + (16 + cl) * 256 + (((s * 4 + rl) ^ (cl & 7)) << 3));
    MF(a0, pb[sl][0], acc[0][0]) MF(a1, pb[sl][0], acc[1][0])
    MF(a0, pb[sl][1], acc[0][1]) MF(a1, pb[sl][1], acc[1][1])
    MF(a0, ub[sl][0], acc[0][2]) MF(a1, ub[sl][0], acc[1][2])
    MF(a0, ub[sl][1], acc[0][3]) MF(a1, ub[sl][1], acc[1][3])
    if (s < 5) LDW1(sl, s + 3)
  }
  __builtin_amdgcn_s_setprio(0);
#undef LDW1
#undef FR1

#pragma unroll
  for (int fm = 0; fm < 2; ++fm)
#pragma unroll
    for (int fn = 0; fn < 2; ++fn)
#pragma unroll
      for (int r = 0; r < 4; ++r) {
        acc[fm][fn][r]     += tp_[fm][fn];
        acc[fm][2 + fn][r] += tu_[fm][fn];
      }

#pragma unroll
  for (int fm = 0; fm < 2; ++fm)
#pragma unroll
    for (int br = 0; br < 2; ++br) {
      f32x4 s = acc[fm][br * 2] + acc[fm][br * 2 + 1];
      f32x4 q = acc[fm][br * 2] * acc[fm][br * 2] + acc[fm][br * 2 + 1] * acc[fm][br * 2 + 1];
#pragma unroll
      for (int o = 1; o < 16; o <<= 1) {
#pragma unroll
        for (int r = 0; r < 4; ++r) {
          s[r] += __shfl_xor(s[r], o);
          q[r] += __shfl_xor(q[r], o);
        }
      }
      if (cl == 0) {
#pragma unroll
        for (int r = 0; r < 4; ++r) {
          int row = fm * 16 + rl * 4 + r;
          lstat[br][row][w]     = s[r];
          lstat[br][row][8 + w] = q[r];
        }
      }
    }
  __syncthreads();                                   // B2

  if (tid < 64) {
    int fb = tid >> 5, row = tid & 31;
    f32x4 a = *(const f32x4*)&lstat[fb][row][0];
    f32x4 b = *(const f32x4*)&lstat[fb][row][4];
    f32x4 c = *(const f32x4*)&lstat[fb][row][8];
    f32x4 d = *(const f32x4*)&lstat[fb][row][12];
    float ss = a[0] + a[1] + a[2] + a[3] + b[0] + b[1] + b[2] + b[3];
    float qq = c[0] + c[1] + c[2] + c[3] + d[0] + d[1] + d[2] + d[3];
    float mu = ss * (1.f / 256.f);
    lfin[fb][row][0] = mu;
    lfin[fb][row][1] = rsqrtf(qq * (1.f / 256.f) - mu * mu + 1e-5f);
  }
  __syncthreads();                                   // B2b

  const int brw = w >> 2, wc = w & 3;
  const u16* hsrc = lsH[brw];
  const float* b2src = brw ? ub2 : pb2;
  float b2v[4];
#pragma unroll
  for (int fn = 0; fn < 4; ++fn) b2v[fn] = b2src[wc * 64 + fn * 16 + cl];

  bf16x8 bq[3][4];
#define FR2(NG, S) (*(const bf16x8*)(W2pk + (size_t)(((NG) * 8 + (S)) * 64 + lane) * 8))
#define LDW2(SL, S) { bq[SL][0] = FR2(brw * 16 + wc * 4,     S); \
                      bq[SL][1] = FR2(brw * 16 + wc * 4 + 1, S); \
                      bq[SL][2] = FR2(brw * 16 + wc * 4 + 2, S); \
                      bq[SL][3] = FR2(brw * 16 + wc * 4 + 3, S); \
                      asm volatile("" ::: "memory"); }
  LDW2(0, 0)

  {
    float gv[2][2], btv[2][2];
#pragma unroll
    for (int fn = 0; fn < 2; ++fn) {
      int col = w * 32 + fn * 16 + cl;
      gv[0][fn] = pg[col];  btv[0][fn] = pbt[col];
      gv[1][fn] = ug[col];  btv[1][fn] = ubt[col];
    }
#pragma unroll
    for (int fm = 0; fm < 2; ++fm) {
      float mean[2][4], rstd[2][4];
#pragma unroll
      for (int r = 0; r < 4; ++r) {
        int row = fm * 16 + rl * 4 + r;
        mean[0][r] = lfin[0][row][0]; rstd[0][r] = lfin[0][row][1];
        mean[1][r] = lfin[1][row][0]; rstd[1][r] = lfin[1][row][1];
      }
#pragma unroll
      for (int br = 0; br < 2; ++br)
#pragma unroll
        for (int fn = 0; fn < 2; ++fn) {
          int col = w * 32 + fn * 16 + cl;
#pragma unroll
          for (int r = 0; r < 4; ++r) {
            int row = fm * 16 + rl * 4 + r;
            float h = fmaxf((acc[fm][br * 2 + fn][r] - mean[br][r]) * rstd[br][r]
                            * gv[br][fn] + btv[br][fn], 0.f);
            lsH[br][row * 256 + (((col >> 3) ^ (row & 7)) << 3) + (col & 7)] = f2bf(h);
          }
        }
    }
  }
#pragma unroll
  for (int i = 0; i < 2; ++i)
#pragma unroll
    for (int j = 0; j < 4; ++j) acc[i][j] = zero;
  __syncthreads();                                   // B3

  LDW2(1, 1) LDW2(2, 2)
  __builtin_amdgcn_s_setprio(1);
#pragma unroll
  for (int s = 0; s < 8; ++s) {
    const int sl = s % 3;
    bf16x8 a0 = *(const bf16x8*)(hsrc + cl * 256 + (((s * 4 + rl) ^ (cl & 7)) << 3));
    bf16x8 a1 = *(const bf16x8*)(hsrc + (16 + cl) * 256 + (((s * 4 + rl) ^ (cl & 7)) << 3));
    MF(a0, bq[sl][0], acc[0][0]) MF(a1, bq[sl][0], acc[1][0])
    MF(a0, bq[sl][1], acc[0][1]) MF(a1, bq[sl][1], acc[1][1])
    MF(a0, bq[sl][2], acc[0][2]) MF(a1, bq[sl][2], acc[1][2])
    MF(a0, bq[sl][3], acc[0][3]) MF(a1, bq[sl][3], acc[1][3])
    if (s < 5) LDW2(sl, s + 3)
  }
  __builtin_amdgcn_s_setprio(0);
#undef LDW2
#undef FR2
#undef MF
  __syncthreads();                                   // B4

  float* xbuf = (float*)&lsH[0][0];
  const int base = wc * 2048;
  if (brw == 0) {
#pragma unroll
    for (int fm = 0; fm < 2; ++fm)
#pragma unroll
      for (int fn = 0; fn < 4; ++fn)
#pragma unroll
        for (int r = 0; r < 4; ++r)
          xbuf[base + ((fm * 4 + fn) * 4 + r) * 64 + lane] = acc[fm][fn][r] + b2v[fn];
  }
  __syncthreads();                                   // B5

  if (brw == 1) {
#pragma unroll
    for (int fm = 0; fm < 2; ++fm)
#pragma unroll
      for (int fn = 0; fn < 4; ++fn)
#pragma unroll
        for (int r = 0; r < 4; ++r) {
          float gp = xbuf[base + ((fm * 4 + fn) * 4 + r) * 64 + lane];
          float gu = acc[fm][fn][r] + b2v[fn];
          int row = blockRow + fm * 16 + rl * 4 + r;
          int col = wc * 64 + fn * 16 + cl;
          size_t idx = (size_t)row * 256 + col;
          outp[idx] = slots[idx] + gp * gu;
        }
  }
}

// ---------------------------------------------------------------------------
// host launcher
// ---------------------------------------------------------------------------
extern "C" void kernel_launch(void* const* d_in, const int* in_sizes, int n_in,
                              void* d_out, int out_size, void* d_ws, size_t ws_size,
                              hipStream_t stream) {
  const float* inst  = (const float*)d_in[0];
  const float* slots = (const float*)d_in[1];
  const float* Wfc   = (const float*)d_in[2];
  const float* bfc   = (const float*)d_in[3];
  const float* Wfp   = (const float*)d_in[4];
  const float* bfp   = (const float*)d_in[5];
  const float* Kc    = (const float*)d_in[6];
  const float* Vc    = (const float*)d_in[7];
  const float* Kp    = (const float*)d_in[8];
  const float* Vp    = (const float*)d_in[9];
  const float* pW1   = (const float*)d_in[10];
  const float* pb1   = (const float*)d_in[11];
  const float* pg    = (const float*)d_in[12];
  const float* pbt   = (const float*)d_in[13];
  const float* pW2   = (const float*)d_in[14];
  const float* pb2   = (const float*)d_in[15];
  const float* uW1   = (const float*)d_in[16];
  const float* ub1   = (const float*)d_in[17];
  const float* ug    = (const float*)d_in[18];
  const float* ubt   = (const float*)d_in[19];
  const float* uW2   = (const float*)d_in[20];
  const float* ub2   = (const float*)d_in[21];
  float* out = (float*)d_out;
  char*  ws  = (char*)d_ws;

  const size_t OFF_INST  = 0;
  const size_t OFF_KC    = OFF_INST  + 6291456;
  const size_t OFF_KP    = OFF_KC    + 786432;
  const size_t OFF_WFCB  = OFF_KP    + 786432;
  const size_t OFF_WFPB  = OFF_WFCB  + 1179648;
  const size_t OFF_VCB   = OFF_WFPB  + 1179648;
  const size_t OFF_VPB   = OFF_VCB   + 786432;
  const size_t OFF_W1TP  = OFF_VPB   + 786432;
  const size_t OFF_W1TU  = OFF_W1TP  + 524288;
  const size_t OFF_W1PK  = OFF_W1TU  + 524288;
  const size_t OFF_W2PK  = OFF_W1PK  + 262144;
  const size_t OFF_KW    = OFF_W2PK  + 262144;
  const size_t OFF_VW1   = OFF_KW    + 1572864;
  const size_t OFF_SB    = OFF_VW1   + 524288;
  const size_t OFF_T     = OFF_SB    + 4096;          // [2][4096][256] bf16
  const size_t OFF_SC    = OFF_T     + 4194304;
  const size_t OFF_P     = OFF_SC    + 8388608;

  u16*   instb = (u16*)(ws + OFF_INST);
  u16*   Kcb   = (u16*)(ws + OFF_KC);
  u16*   Kpb   = (u16*)(ws + OFF_KP);
  u16*   Wfcb  = (u16*)(ws + OFF_WFCB);
  u16*   Wfpb  = (u16*)(ws + OFF_WFPB);
  u16*   Vcb   = (u16*)(ws + OFF_VCB);
  u16*   Vpb   = (u16*)(ws + OFF_VPB);
  u16*   W1Tp  = (u16*)(ws + OFF_W1TP);
  u16*   W1Tu  = (u16*)(ws + OFF_W1TU);
  u16*   W1pk  = (u16*)(ws + OFF_W1PK);
  u16*   W2pk  = (u16*)(ws + OFF_W2PK);
  u16*   KWc   = (u16*)(ws + OFF_KW);
  u16*   KWp   = KWc + (size_t)NC * PP;
  u16*   VW1p  = (u16*)(ws + OFF_VW1);
  u16*   VW1u  = VW1p + (size_t)SLOT * NC;
  float* sb    = (float*)(ws + OFF_SB);
  u16*   t0    = (u16*)(ws + OFF_T);
  u16*   t1    = t0 + (size_t)BB * SLOT;
  u16*   scH   = (u16*)(ws + OFF_SC);
  u16*   Pb    = (u16*)(ws + OFF_P);

  prep_all<<<dim3(6592), 256, 0, stream>>>(
      inst, Kc, Kp, Wfc, Wfp, Vc, Vp, pW1, uW1, pW2, uW2, bfc, bfp,
      instb, Kcb, Kpb, Wfcb, Wfpb, Vcb, Vpb, W1Tp, W1Tu, W1pk, W2pk, sb);

  gemm_mixed<<<dim3(256), 256, 0, stream>>>(
      Kcb, Kpb, Wfcb, Wfpb, KWc, KWp, W1Tp, W1Tu, Vcb, Vpb, VW1p, VW1u);

  gemm_scores<<<dim3(64, 16), 256, 0, stream>>>(instb, KWc, sb, scH);

  softmax_rows<<<dim3(2048), 256, 0, stream>>>(scH, Pb);

  gemm_t<<<dim3(64, 4, 2), 256, 0, stream>>>(Pb, VW1p, VW1u, pb1, ub1, t0, t1);

  fused_update<<<dim3(1024), 512, 0, stream>>>(
      slots, t0, t1, W1pk, W2pk, pg, pbt, ug, ubt, pb2, ub2, out);

  (void)in_sizes; (void)n_in; (void)out_size; (void)ws_size;
}